// Round 1
// 353.683 us; speedup vs baseline: 1.0079x; 1.0079x over previous
//
#include <hip/hip_runtime.h>

#define BATCH 4096
#define ISZ   512
#define MT    8
#define NH    4
#define KS    8
#define NFEAT (NH * ISZ * KS)   // 16384
#define LN_EPS 1e-5f
#define ROWS  4                  // batch rows per block

typedef float vfloat4 __attribute__((ext_vector_type(4)));

// Chebyshev-basis (8 coeffs, poly already folded in) -> monomial coeffs.
// T0..T7 monomial expansion:
//  x^0: w0 - w2 + w4 - w6          x^1: w1 - 3w3 + 5w5 - 7w7
//  x^2: 2w2 - 8w4 + 18w6           x^3: 4w3 - 20w5 + 56w7
//  x^4: 8w4 - 48w6                 x^5: 16w5 - 112w7
//  x^6: 32w6                       x^7: 64w7
__device__ __forceinline__ void cheb2mono(const float w[8], float4& m0, float4& m1) {
    m0.x = w[0] - w[2] + w[4] - w[6];
    m0.y = w[1] - 3.f*w[3] + 5.f*w[5] - 7.f*w[7];
    m0.z = 2.f*w[2] - 8.f*w[4] + 18.f*w[6];
    m0.w = 4.f*w[3] - 20.f*w[5] + 56.f*w[7];
    m1.x = 8.f*w[4] - 48.f*w[6];
    m1.y = 16.f*w[5] - 112.f*w[7];
    m1.z = 32.f*w[6];
    m1.w = 64.f*w[7];
}

// One thread per feature f (16384 total): load the 8 Chebyshev-basis weights,
// fold poly, convert to monomial, store two float4 rows of the lane-swizzled
// table so the main kernel's wa[q] = W2v[(j*8+q)*512 + t] is a contiguous
// global_load_dwordx4 across lanes.
__global__ void prep_w2(const float* __restrict__ kern, const float* __restrict__ poly,
                        float4* __restrict__ W2) {
    const int f = blockIdx.x * 256 + threadIdx.x;   // 0..16383
    const int j = f >> 11;                          // f = j*2048 + t*4 + c
    const int t = (f >> 2) & 511;
    const int c = f & 3;
    const int base = (f >> 3) * 64 + (f & 7);       // kernels [h][i][m][k]
    const float p = poly[f];
    float w[8];
    #pragma unroll
    for (int m = 0; m < 8; ++m) w[m] = kern[base + m * 8] * p;
    float4 m0, m1;
    cheb2mono(w, m0, m1);
    W2[(j * 8 + 2 * c    ) * 512 + t] = m0;   // powers 0..3
    W2[(j * 8 + 2 * c + 1) * 512 + t] = m1;   // powers 4..7
}

__device__ __forceinline__ float fast_silu(float d) {
    // exp, add, rcp, mul. rcp(inf)=0 gives correct saturation.
    return d * __builtin_amdgcn_rcpf(1.f + __expf(-d));
}

// Degree-7 Horner: 7 FMA, scalar x input (no Chebyshev basis rebuild).
__device__ __forceinline__ float horner8(float4 w0, float4 w1, float x) {
    float s = w1.w;
    s = fmaf(s, x, w1.z);
    s = fmaf(s, x, w1.y);
    s = fmaf(s, x, w1.x);
    s = fmaf(s, x, w0.w);
    s = fmaf(s, x, w0.z);
    s = fmaf(s, x, w0.y);
    s = fmaf(s, x, w0.x);
    return s;
}

template <bool USE_W2>
__global__ __launch_bounds__(512, 4)   // cap 128 VGPR -> 2 blocks/CU
void cheb_main(const float* __restrict__ x, const float* __restrict__ scale,
               const float4* __restrict__ W2v, const float* __restrict__ kern,
               const float* __restrict__ poly,
               const float* __restrict__ gamma, const float* __restrict__ beta,
               float* __restrict__ out) {
    __shared__ float xs[ROWS][ISZ];      // 8 KB scaled inputs
    __shared__ float red[8][2 * ROWS];   // per-wave LN partials

    const int t  = threadIdx.x;
    const int r0 = blockIdx.x * ROWS;

    #pragma unroll
    for (int idx = t; idx < ROWS * ISZ; idx += 512) {
        const int r = idx >> 9, i = idx & 511;
        xs[r][i] = x[(r0 + r) * ISZ + i] * scale[i];
    }
    __syncthreads();

    float sum[ROWS], sq[ROWS];
    #pragma unroll
    for (int r = 0; r < ROWS; ++r) { sum[r] = 0.f; sq[r] = 0.f; }

    // ---- Pass A: LN statistics ----
    #pragma unroll
    for (int j = 0; j < 8; ++j) {
        const int i = ((j & 1) << 8) + (t >> 1);   // this thread's input feature
        float4 wa[8];
        if (USE_W2) {
            #pragma unroll
            for (int q = 0; q < 8; ++q) wa[q] = W2v[(j * 8 + q) * 512 + t];
        } else {
            #pragma unroll
            for (int c = 0; c < 4; ++c) {
                const int f = j * 2048 + t * 4 + c;
                const int base = (f >> 3) * 64 + (f & 7);
                const float p = poly[f];
                float w[8];
                #pragma unroll
                for (int m = 0; m < 8; ++m) w[m] = kern[base + m * 8] * p;
                cheb2mono(w, wa[2 * c], wa[2 * c + 1]);
            }
        }
        float xv[ROWS];
        #pragma unroll
        for (int r = 0; r < ROWS; ++r) xv[r] = xs[r][i];   // broadcast LDS reads
        #pragma unroll
        for (int c = 0; c < 4; ++c) {
            #pragma unroll
            for (int r = 0; r < ROWS; ++r) {
                const float s = fast_silu(horner8(wa[2 * c], wa[2 * c + 1], xv[r]));
                sum[r] += s;
                sq[r]   = fmaf(s, s, sq[r]);
            }
        }
    }

    // Wave butterfly + cross-wave combine
    #pragma unroll
    for (int off = 32; off > 0; off >>= 1) {
        #pragma unroll
        for (int r = 0; r < ROWS; ++r) {
            sum[r] += __shfl_xor(sum[r], off, 64);
            sq[r]  += __shfl_xor(sq[r],  off, 64);
        }
    }
    const int wave = t >> 6;
    if ((t & 63) == 0) {
        #pragma unroll
        for (int r = 0; r < ROWS; ++r) {
            red[wave][r]        = sum[r];
            red[wave][ROWS + r] = sq[r];
        }
    }
    __syncthreads();

    float rs[ROWS], nm[ROWS];
    {
        const float invN = 1.f / (float)NFEAT;
        #pragma unroll
        for (int r = 0; r < ROWS; ++r) {
            float ts = 0.f, tq = 0.f;
            #pragma unroll
            for (int wv = 0; wv < 8; ++wv) { ts += red[wv][r]; tq += red[wv][ROWS + r]; }
            const float mean = ts * invN;
            rs[r] = rsqrtf(fmaxf(tq * invN - mean * mean, 0.f) + LN_EPS);
            nm[r] = -mean * rs[r];
        }
    }

    // ---- Pass B: recompute, normalize (2 FMA/elem), nontemporal float4 stores ----
    #pragma unroll
    for (int j = 0; j < 8; ++j) {
        const int i  = ((j & 1) << 8) + (t >> 1);
        const int f0 = j * 2048 + t * 4;
        float4 wa[8];
        if (USE_W2) {
            #pragma unroll
            for (int q = 0; q < 8; ++q) wa[q] = W2v[(j * 8 + q) * 512 + t];
        } else {
            #pragma unroll
            for (int c = 0; c < 4; ++c) {
                const int f = f0 + c;
                const int base = (f >> 3) * 64 + (f & 7);
                const float p = poly[f];
                float w[8];
                #pragma unroll
                for (int m = 0; m < 8; ++m) w[m] = kern[base + m * 8] * p;
                cheb2mono(w, wa[2 * c], wa[2 * c + 1]);
            }
        }
        float xv[ROWS];
        #pragma unroll
        for (int r = 0; r < ROWS; ++r) xv[r] = xs[r][i];
        const float4 g  = *(const float4*)(gamma + f0);
        const float4 bb = *(const float4*)(beta  + f0);
        vfloat4 rv[ROWS];
        #pragma unroll
        for (int c = 0; c < 4; ++c) {
            const float gc = (c == 0) ? g.x  : (c == 1) ? g.y  : (c == 2) ? g.z  : g.w;
            const float bc = (c == 0) ? bb.x : (c == 1) ? bb.y : (c == 2) ? bb.z : bb.w;
            #pragma unroll
            for (int r = 0; r < ROWS; ++r) {
                const float s = fast_silu(horner8(wa[2 * c], wa[2 * c + 1], xv[r]));
                rv[r][c] = fmaf(fmaf(s, rs[r], nm[r]), gc, bc);
            }
        }
        #pragma unroll
        for (int r = 0; r < ROWS; ++r)
            __builtin_nontemporal_store(rv[r],
                (vfloat4*)(out + (size_t)(r0 + r) * NFEAT + f0));
    }
}

extern "C" void kernel_launch(void* const* d_in, const int* in_sizes, int n_in,
                              void* d_out, int out_size, void* d_ws, size_t ws_size,
                              hipStream_t stream) {
    const float* x     = (const float*)d_in[0];
    const float* scale = (const float*)d_in[1];
    const float* poly  = (const float*)d_in[2];
    const float* kern  = (const float*)d_in[3];
    const float* gamma = (const float*)d_in[4];
    const float* beta  = (const float*)d_in[5];
    float* out = (float*)d_out;

    const size_t W2_BYTES = (size_t)NFEAT * 8 * sizeof(float);  // 512 KB
    if (ws_size >= W2_BYTES) {
        float4* W2 = (float4*)d_ws;
        prep_w2<<<NFEAT / 256, 256, 0, stream>>>(kern, poly, W2);
        cheb_main<true><<<BATCH / ROWS, 512, 0, stream>>>(x, scale, (const float4*)W2,
                                                          kern, poly, gamma, beta, out);
    } else {
        cheb_main<false><<<BATCH / ROWS, 512, 0, stream>>>(x, scale, nullptr,
                                                           kern, poly, gamma, beta, out);
    }
}

// Round 3
// 353.384 us; speedup vs baseline: 1.0087x; 1.0008x over previous
//
#include <hip/hip_runtime.h>

#define BATCH 4096
#define ISZ   512
#define MT    8
#define NH    4
#define KS    8
#define NFEAT (NH * ISZ * KS)   // 16384
#define LN_EPS 1e-5f
#define ROWS  4                  // batch rows per block

typedef float vfloat4 __attribute__((ext_vector_type(4)));

// Chebyshev-basis (8 coeffs, poly already folded in) -> monomial coeffs.
// T0..T7 monomial expansion:
//  x^0: w0 - w2 + w4 - w6          x^1: w1 - 3w3 + 5w5 - 7w7
//  x^2: 2w2 - 8w4 + 18w6           x^3: 4w3 - 20w5 + 56w7
//  x^4: 8w4 - 48w6                 x^5: 16w5 - 112w7
//  x^6: 32w6                       x^7: 64w7
__device__ __forceinline__ void cheb2mono(const float w[8], float4& m0, float4& m1) {
    m0.x = w[0] - w[2] + w[4] - w[6];
    m0.y = w[1] - 3.f*w[3] + 5.f*w[5] - 7.f*w[7];
    m0.z = 2.f*w[2] - 8.f*w[4] + 18.f*w[6];
    m0.w = 4.f*w[3] - 20.f*w[5] + 56.f*w[7];
    m1.x = 8.f*w[4] - 48.f*w[6];
    m1.y = 16.f*w[5] - 112.f*w[7];
    m1.z = 32.f*w[6];
    m1.w = 64.f*w[7];
}

// One thread per feature f (16384 total): load the 8 Chebyshev-basis weights,
// fold poly, convert to monomial, store two float4 rows of the lane-swizzled
// table so the main kernel's wa[q] = W2v[(j*8+q)*512 + t] is a contiguous
// global_load_dwordx4 across lanes.
__global__ void prep_w2(const float* __restrict__ kern, const float* __restrict__ poly,
                        float4* __restrict__ W2) {
    const int f = blockIdx.x * 256 + threadIdx.x;   // 0..16383
    const int j = f >> 11;                          // f = j*2048 + t*4 + c
    const int t = (f >> 2) & 511;
    const int c = f & 3;
    const int base = (f >> 3) * 64 + (f & 7);       // kernels [h][i][m][k]
    const float p = poly[f];
    float w[8];
    #pragma unroll
    for (int m = 0; m < 8; ++m) w[m] = kern[base + m * 8] * p;
    float4 m0, m1;
    cheb2mono(w, m0, m1);
    W2[(j * 8 + 2 * c    ) * 512 + t] = m0;   // powers 0..3
    W2[(j * 8 + 2 * c + 1) * 512 + t] = m1;   // powers 4..7
}

__device__ __forceinline__ float fast_silu(float d) {
    // exp, add, rcp, mul. rcp(inf)=0 gives correct saturation.
    return d * __builtin_amdgcn_rcpf(1.f + __expf(-d));
}

// Degree-7 Horner: 7 FMA, scalar x input (no Chebyshev basis rebuild).
__device__ __forceinline__ float horner8(float4 w0, float4 w1, float x) {
    float s = w1.w;
    s = fmaf(s, x, w1.z);
    s = fmaf(s, x, w1.y);
    s = fmaf(s, x, w1.x);
    s = fmaf(s, x, w0.w);
    s = fmaf(s, x, w0.z);
    s = fmaf(s, x, w0.y);
    s = fmaf(s, x, w0.x);
    return s;
}

template <bool USE_W2>
__global__ __launch_bounds__(512, 4)   // cap 128 VGPR -> 2 blocks/CU
void cheb_main(const float* __restrict__ x, const float* __restrict__ scale,
               const float4* __restrict__ W2v, const float* __restrict__ kern,
               const float* __restrict__ poly,
               const float* __restrict__ gamma, const float* __restrict__ beta,
               float* __restrict__ out) {
    __shared__ float xs[ROWS][ISZ];      // 8 KB scaled inputs
    __shared__ float red[8][2 * ROWS];   // per-wave LN partials

    const int t  = threadIdx.x;
    const int r0 = blockIdx.x * ROWS;

    #pragma unroll
    for (int idx = t; idx < ROWS * ISZ; idx += 512) {
        const int r = idx >> 9, i = idx & 511;
        xs[r][i] = x[(r0 + r) * ISZ + i] * scale[i];
    }
    __syncthreads();

    float sum[ROWS], sq[ROWS];
    #pragma unroll
    for (int r = 0; r < ROWS; ++r) { sum[r] = 0.f; sq[r] = 0.f; }

    // ---- Pass A: LN statistics ----
    #pragma unroll
    for (int j = 0; j < 8; ++j) {
        const int i = ((j & 1) << 8) + (t >> 1);   // this thread's input feature
        float4 wa[8];
        if (USE_W2) {
            #pragma unroll
            for (int q = 0; q < 8; ++q) wa[q] = W2v[(j * 8 + q) * 512 + t];
        } else {
            #pragma unroll
            for (int c = 0; c < 4; ++c) {
                const int f = j * 2048 + t * 4 + c;
                const int base = (f >> 3) * 64 + (f & 7);
                const float p = poly[f];
                float w[8];
                #pragma unroll
                for (int m = 0; m < 8; ++m) w[m] = kern[base + m * 8] * p;
                cheb2mono(w, wa[2 * c], wa[2 * c + 1]);
            }
        }
        float xv[ROWS];
        #pragma unroll
        for (int r = 0; r < ROWS; ++r) xv[r] = xs[r][i];   // broadcast LDS reads
        #pragma unroll
        for (int c = 0; c < 4; ++c) {
            #pragma unroll
            for (int r = 0; r < ROWS; ++r) {
                const float s = fast_silu(horner8(wa[2 * c], wa[2 * c + 1], xv[r]));
                sum[r] += s;
                sq[r]   = fmaf(s, s, sq[r]);
            }
        }
    }

    // Wave butterfly + cross-wave combine
    #pragma unroll
    for (int off = 32; off > 0; off >>= 1) {
        #pragma unroll
        for (int r = 0; r < ROWS; ++r) {
            sum[r] += __shfl_xor(sum[r], off, 64);
            sq[r]  += __shfl_xor(sq[r],  off, 64);
        }
    }
    const int wave = t >> 6;
    if ((t & 63) == 0) {
        #pragma unroll
        for (int r = 0; r < ROWS; ++r) {
            red[wave][r]        = sum[r];
            red[wave][ROWS + r] = sq[r];
        }
    }
    __syncthreads();

    float rs[ROWS], nm[ROWS];
    {
        const float invN = 1.f / (float)NFEAT;
        #pragma unroll
        for (int r = 0; r < ROWS; ++r) {
            float ts = 0.f, tq = 0.f;
            #pragma unroll
            for (int wv = 0; wv < 8; ++wv) { ts += red[wv][r]; tq += red[wv][ROWS + r]; }
            const float mean = ts * invN;
            rs[r] = rsqrtf(fmaxf(tq * invN - mean * mean, 0.f) + LN_EPS);
            nm[r] = -mean * rs[r];
        }
    }

    // ---- Pass B: recompute, normalize (2 FMA/elem), nontemporal float4 stores ----
    #pragma unroll
    for (int j = 0; j < 8; ++j) {
        const int i  = ((j & 1) << 8) + (t >> 1);
        const int f0 = j * 2048 + t * 4;
        float4 wa[8];
        if (USE_W2) {
            #pragma unroll
            for (int q = 0; q < 8; ++q) wa[q] = W2v[(j * 8 + q) * 512 + t];
        } else {
            #pragma unroll
            for (int c = 0; c < 4; ++c) {
                const int f = f0 + c;
                const int base = (f >> 3) * 64 + (f & 7);
                const float p = poly[f];
                float w[8];
                #pragma unroll
                for (int m = 0; m < 8; ++m) w[m] = kern[base + m * 8] * p;
                cheb2mono(w, wa[2 * c], wa[2 * c + 1]);
            }
        }
        float xv[ROWS];
        #pragma unroll
        for (int r = 0; r < ROWS; ++r) xv[r] = xs[r][i];
        const float4 g  = *(const float4*)(gamma + f0);
        const float4 bb = *(const float4*)(beta  + f0);
        vfloat4 rv[ROWS];
        #pragma unroll
        for (int c = 0; c < 4; ++c) {
            const float gc = (c == 0) ? g.x  : (c == 1) ? g.y  : (c == 2) ? g.z  : g.w;
            const float bc = (c == 0) ? bb.x : (c == 1) ? bb.y : (c == 2) ? bb.z : bb.w;
            #pragma unroll
            for (int r = 0; r < ROWS; ++r) {
                const float s = fast_silu(horner8(wa[2 * c], wa[2 * c + 1], xv[r]));
                rv[r][c] = fmaf(fmaf(s, rs[r], nm[r]), gc, bc);
            }
        }
        #pragma unroll
        for (int r = 0; r < ROWS; ++r)
            __builtin_nontemporal_store(rv[r],
                (vfloat4*)(out + (size_t)(r0 + r) * NFEAT + f0));
    }
}

extern "C" void kernel_launch(void* const* d_in, const int* in_sizes, int n_in,
                              void* d_out, int out_size, void* d_ws, size_t ws_size,
                              hipStream_t stream) {
    const float* x     = (const float*)d_in[0];
    const float* scale = (const float*)d_in[1];
    const float* poly  = (const float*)d_in[2];
    const float* kern  = (const float*)d_in[3];
    const float* gamma = (const float*)d_in[4];
    const float* beta  = (const float*)d_in[5];
    float* out = (float*)d_out;

    const size_t W2_BYTES = (size_t)NFEAT * 8 * sizeof(float);  // 512 KB
    if (ws_size >= W2_BYTES) {
        float4* W2 = (float4*)d_ws;
        prep_w2<<<NFEAT / 256, 256, 0, stream>>>(kern, poly, W2);
        cheb_main<true><<<BATCH / ROWS, 512, 0, stream>>>(x, scale, (const float4*)W2,
                                                          kern, poly, gamma, beta, out);
    } else {
        cheb_main<false><<<BATCH / ROWS, 512, 0, stream>>>(x, scale, nullptr,
                                                           kern, poly, gamma, beta, out);
    }
}

// Round 4
// 311.157 us; speedup vs baseline: 1.1456x; 1.1357x over previous
//
#include <hip/hip_runtime.h>

#define BATCH 4096
#define ISZ   512
#define MT    8
#define NH    4
#define KS    8
#define NFEAT (NH * ISZ * KS)   // 16384
#define LN_EPS 1e-5f
#define ROWS  4                  // batch rows per block

typedef float vfloat4 __attribute__((ext_vector_type(4)));

// Chebyshev-basis (8 coeffs, poly folded) -> monomial coeffs.
__device__ __forceinline__ void cheb2mono(const float w[8], float4& m0, float4& m1) {
    m0.x = w[0] - w[2] + w[4] - w[6];
    m0.y = w[1] - 3.f*w[3] + 5.f*w[5] - 7.f*w[7];
    m0.z = 2.f*w[2] - 8.f*w[4] + 18.f*w[6];
    m0.w = 4.f*w[3] - 20.f*w[5] + 56.f*w[7];
    m1.x = 8.f*w[4] - 48.f*w[6];
    m1.y = 16.f*w[5] - 112.f*w[7];
    m1.z = 32.f*w[6];
    m1.w = 64.f*w[7];
}

// One thread per feature f: fold poly, convert to monomial, store lane-swizzled
// so wa[q] = W2v[(j*8+q)*512 + t] is a contiguous global_load_dwordx4.
__global__ void prep_w2(const float* __restrict__ kern, const float* __restrict__ poly,
                        float4* __restrict__ W2) {
    const int f = blockIdx.x * 256 + threadIdx.x;   // 0..16383
    const int j = f >> 11;                          // f = j*2048 + t*4 + c
    const int t = (f >> 2) & 511;
    const int c = f & 3;
    const int base = (f >> 3) * 64 + (f & 7);       // kernels [h][i][m][k]
    const float p = poly[f];
    float w[8];
    #pragma unroll
    for (int m = 0; m < 8; ++m) w[m] = kern[base + m * 8] * p;
    float4 m0, m1;
    cheb2mono(w, m0, m1);
    W2[(j * 8 + 2 * c    ) * 512 + t] = m0;   // powers 0..3
    W2[(j * 8 + 2 * c + 1) * 512 + t] = m1;   // powers 4..7
}

__device__ __forceinline__ float fast_silu(float d) {
    // exp, add, rcp, mul. rcp(inf)=0 gives correct saturation.
    return d * __builtin_amdgcn_rcpf(1.f + __expf(-d));
}

// Degree-7 Horner: 7 FMA, scalar x input.
__device__ __forceinline__ float horner8(float4 w0, float4 w1, float x) {
    float s = w1.w;
    s = fmaf(s, x, w1.z);
    s = fmaf(s, x, w1.y);
    s = fmaf(s, x, w1.x);
    s = fmaf(s, x, w0.w);
    s = fmaf(s, x, w0.z);
    s = fmaf(s, x, w0.y);
    s = fmaf(s, x, w0.x);
    return s;
}

// Fallback-path weight materialization for one c (no workspace).
__device__ __forceinline__ void make_w(const float* kern, const float* poly,
                                       int f, float4& m0, float4& m1) {
    const int base = (f >> 3) * 64 + (f & 7);
    const float p = poly[f];
    float w[8];
    #pragma unroll
    for (int m = 0; m < 8; ++m) w[m] = kern[base + m * 8] * p;
    cheb2mono(w, m0, m1);
}

template <bool USE_W2>
__global__ __launch_bounds__(512, 4)   // 128 VGPR cap -> 2 blocks/CU; bound now slack
void cheb_main(const float* __restrict__ x, const float* __restrict__ scale,
               const float4* __restrict__ W2v, const float* __restrict__ kern,
               const float* __restrict__ poly,
               const float* __restrict__ gamma, const float* __restrict__ beta,
               float* __restrict__ out) {
    __shared__ float xs[ROWS][ISZ];      // 8 KB scaled inputs
    __shared__ float red[8][2 * ROWS];   // per-wave LN partials

    const int t  = threadIdx.x;
    const int r0 = blockIdx.x * ROWS;

    #pragma unroll
    for (int idx = t; idx < ROWS * ISZ; idx += 512) {
        const int r = idx >> 9, i = idx & 511;
        xs[r][i] = x[(r0 + r) * ISZ + i] * scale[i];
    }
    __syncthreads();

    float sum[ROWS], sq[ROWS];
    #pragma unroll
    for (int r = 0; r < ROWS; ++r) { sum[r] = 0.f; sq[r] = 0.f; }

    // ---- Pass A: LN statistics ----
    // j-loop NOT unrolled: keeps weight live-set small (2 float4 per c),
    // lets the allocator stay under the 128-VGPR bound without spilling.
    #pragma unroll 1
    for (int j = 0; j < 8; ++j) {
        const int i = ((j & 1) << 8) + (t >> 1);
        float xv[ROWS];
        #pragma unroll
        for (int r = 0; r < ROWS; ++r) xv[r] = xs[r][i];   // broadcast LDS reads
        const float4* Wj = W2v + (size_t)j * 8 * 512 + t;
        #pragma unroll
        for (int c = 0; c < 4; ++c) {
            float4 w0, w1;
            if (USE_W2) {
                w0 = Wj[(2 * c) * 512];
                w1 = Wj[(2 * c + 1) * 512];
            } else {
                make_w(kern, poly, j * 2048 + t * 4 + c, w0, w1);
            }
            #pragma unroll
            for (int r = 0; r < ROWS; ++r) {
                const float s = fast_silu(horner8(w0, w1, xv[r]));
                sum[r] += s;
                sq[r]   = fmaf(s, s, sq[r]);
            }
        }
    }

    // Wave butterfly + cross-wave combine
    #pragma unroll
    for (int off = 32; off > 0; off >>= 1) {
        #pragma unroll
        for (int r = 0; r < ROWS; ++r) {
            sum[r] += __shfl_xor(sum[r], off, 64);
            sq[r]  += __shfl_xor(sq[r],  off, 64);
        }
    }
    const int wave = t >> 6;
    if ((t & 63) == 0) {
        #pragma unroll
        for (int r = 0; r < ROWS; ++r) {
            red[wave][r]        = sum[r];
            red[wave][ROWS + r] = sq[r];
        }
    }
    __syncthreads();

    float rs[ROWS], nm[ROWS];
    {
        const float invN = 1.f / (float)NFEAT;
        #pragma unroll
        for (int r = 0; r < ROWS; ++r) {
            float ts = 0.f, tq = 0.f;
            #pragma unroll
            for (int wv = 0; wv < 8; ++wv) { ts += red[wv][r]; tq += red[wv][ROWS + r]; }
            const float mean = ts * invN;
            rs[r] = rsqrtf(fmaxf(tq * invN - mean * mean, 0.f) + LN_EPS);
            nm[r] = -mean * rs[r];
        }
    }

    // ---- Pass B: recompute, normalize, nontemporal float4 stores ----
    #pragma unroll 1
    for (int j = 0; j < 8; ++j) {
        const int i  = ((j & 1) << 8) + (t >> 1);
        const int f0 = j * 2048 + t * 4;
        float xv[ROWS];
        #pragma unroll
        for (int r = 0; r < ROWS; ++r) xv[r] = xs[r][i];
        const float4 g  = *(const float4*)(gamma + f0);
        const float4 bb = *(const float4*)(beta  + f0);
        const float4* Wj = W2v + (size_t)j * 8 * 512 + t;
        vfloat4 rv[ROWS];
        #pragma unroll
        for (int c = 0; c < 4; ++c) {
            float4 w0, w1;
            if (USE_W2) {
                w0 = Wj[(2 * c) * 512];
                w1 = Wj[(2 * c + 1) * 512];
            } else {
                make_w(kern, poly, f0 + c, w0, w1);
            }
            const float gc = (c == 0) ? g.x  : (c == 1) ? g.y  : (c == 2) ? g.z  : g.w;
            const float bc = (c == 0) ? bb.x : (c == 1) ? bb.y : (c == 2) ? bb.z : bb.w;
            #pragma unroll
            for (int r = 0; r < ROWS; ++r) {
                const float s = fast_silu(horner8(w0, w1, xv[r]));
                rv[r][c] = fmaf(fmaf(s, rs[r], nm[r]), gc, bc);
            }
        }
        #pragma unroll
        for (int r = 0; r < ROWS; ++r)
            __builtin_nontemporal_store(rv[r],
                (vfloat4*)(out + (size_t)(r0 + r) * NFEAT + f0));
    }
}

extern "C" void kernel_launch(void* const* d_in, const int* in_sizes, int n_in,
                              void* d_out, int out_size, void* d_ws, size_t ws_size,
                              hipStream_t stream) {
    const float* x     = (const float*)d_in[0];
    const float* scale = (const float*)d_in[1];
    const float* poly  = (const float*)d_in[2];
    const float* kern  = (const float*)d_in[3];
    const float* gamma = (const float*)d_in[4];
    const float* beta  = (const float*)d_in[5];
    float* out = (float*)d_out;

    const size_t W2_BYTES = (size_t)NFEAT * 8 * sizeof(float);  // 512 KB
    if (ws_size >= W2_BYTES) {
        float4* W2 = (float4*)d_ws;
        prep_w2<<<NFEAT / 256, 256, 0, stream>>>(kern, poly, W2);
        cheb_main<true><<<BATCH / ROWS, 512, 0, stream>>>(x, scale, (const float4*)W2,
                                                          kern, poly, gamma, beta, out);
    } else {
        cheb_main<false><<<BATCH / ROWS, 512, 0, stream>>>(x, scale, nullptr,
                                                           kern, poly, gamma, beta, out);
    }
}